// Round 4
// baseline (1981.239 us; speedup 1.0000x reference)
//
#include <hip/hip_runtime.h>
#include <math.h>

#define T_DIM 2048
#define F_DIM 513
#define N_ITER 10

// ws float offsets
#define OFF_W    0        // 513*36*2 = 36936 floats (complex W[f][k][m])
#define OFF_WT   36936    // 6*2048   = 12288 floats
#define OFF_P0   49224    // 513*2 partial pairs (parity 0)
#define OFF_P1   50250    // 513*2 partial pairs (parity 1)

// -------- transpose X (K,T,F) -> Xt (F,K,T), + init W=I and partial buffers --------
__global__ __launch_bounds__(256) void transp(const float2* __restrict__ X,
                                              float2* __restrict__ Xt,
                                              float* __restrict__ ws) {
    const int fb  = blockIdx.x + 64 * (blockIdx.y + 17 * blockIdx.z);
    const int tid = threadIdx.x;
    if (fb < 73) {
        int idx = fb * 256 + tid;              // entry index into W (F*36 = 18468)
        if (idx < F_DIM * 36) {
            int e = idx % 36;
            ws[OFF_W + 2 * idx]     = ((e / 6) == (e % 6)) ? 1.0f : 0.0f;
            ws[OFF_W + 2 * idx + 1] = 0.0f;
        }
    } else if (fb < 78) {
        int idx = (fb - 73) * 256 + tid;       // 2*513 = 1026 floats each buffer
        if (idx < 2 * F_DIM) { ws[OFF_P0 + idx] = 1.0f; ws[OFF_P1 + idx] = 1.0f; }
    }

    __shared__ float2 tile[32][33];
    const int k  = blockIdx.z;
    const int t0 = blockIdx.x * 32;
    const int f0 = blockIdx.y * 32;
    const int tx = tid & 31, ty = tid >> 5;    // tx 0..31, ty 0..7
#pragma unroll
    for (int j = 0; j < 4; ++j) {
        int t = t0 + ty + j * 8;
        int f = f0 + tx;
        if (f < F_DIM) tile[ty + j * 8][tx] = X[((size_t)k * T_DIM + t) * F_DIM + f];
    }
    __syncthreads();
#pragma unroll
    for (int j = 0; j < 4; ++j) {
        int f = f0 + ty + j * 8;
        int t = t0 + tx;
        if (f < F_DIM) Xt[((size_t)f * 6 + k) * T_DIM + t] = tile[tx][ty + j * 8];
    }
}

// -------- pass A: wt[k,t] = 1/clip(sqrt(clip(sum_f |(W X)|^2))), 4 t's per block --------
__global__ __launch_bounds__(512, 4) void passA(const float2* __restrict__ X,
                                                float* __restrict__ ws,
                                                const float* __restrict__ pin) {
    __shared__ float sred[192];
    const int tid = threadIdx.x, wave = tid >> 6, lane = tid & 63;

    // convergence check from previous iteration's partials (redundant per block)
    {
        float d2 = 0.f, o2 = 0.f;
        for (int i = tid; i < F_DIM; i += 512) { d2 += pin[2 * i]; o2 += pin[2 * i + 1]; }
#pragma unroll
        for (int d = 1; d < 64; d <<= 1) { d2 += __shfl_xor(d2, d); o2 += __shfl_xor(o2, d); }
        if (lane == 0) { sred[wave * 2] = d2; sred[wave * 2 + 1] = o2; }
        __syncthreads();
        d2 = 0.f; o2 = 0.f;
#pragma unroll
        for (int w = 0; w < 8; ++w) { d2 += sred[w * 2]; o2 += sred[w * 2 + 1]; }
        float rel = sqrtf(d2) / fmaxf(sqrtf(o2), 1.1920929e-07f);
        __syncthreads();
        if (rel < 1e-5f) return;
    }

    const float2* Wc = (const float2*)(ws + OFF_W);
    float* wt = ws + OFF_WT;
    const int t0 = blockIdx.x * 4;

    float s[24];
#pragma unroll
    for (int i = 0; i < 24; ++i) s[i] = 0.0f;

    for (int f = tid; f < F_DIM; f += 512) {
        float2 w[36];
#pragma unroll
        for (int i = 0; i < 36; ++i) w[i] = Wc[f * 36 + i];
#pragma unroll
        for (int tl = 0; tl < 4; ++tl) {
            int t = t0 + tl;
            float2 x[6];
#pragma unroll
            for (int m = 0; m < 6; ++m) x[m] = X[((size_t)m * T_DIM + t) * F_DIM + f];
#pragma unroll
            for (int k = 0; k < 6; ++k) {
                float yr = 0.f, yi = 0.f;
#pragma unroll
                for (int m = 0; m < 6; ++m) {
                    float2 wk = w[k * 6 + m];
                    yr += wk.x * x[m].x - wk.y * x[m].y;
                    yi += wk.x * x[m].y + wk.y * x[m].x;
                }
                s[k * 4 + tl] += yr * yr + yi * yi;
            }
        }
    }
#pragma unroll
    for (int i = 0; i < 24; ++i) {
        float v = s[i];
#pragma unroll
        for (int d = 1; d < 64; d <<= 1) v += __shfl_xor(v, d);
        s[i] = v;
    }
    if (lane == 0) {
#pragma unroll
        for (int i = 0; i < 24; ++i) sred[wave * 24 + i] = s[i];
    }
    __syncthreads();
    if (tid < 24) {
        float r2 = 0.f;
#pragma unroll
        for (int w = 0; w < 8; ++w) r2 += sred[w * 24 + tid];
        int k = tid >> 2, tl = tid & 3;
        float r = sqrtf(fmaxf(r2, 1e-10f));
        wt[k * T_DIM + t0 + tl] = 1.0f / fmaxf(r, 1e-10f);
    }
}

// -------- pass B+C: V[f] in LDS, ISS update of W[f], write diff partials --------
// 8 waves: wave = (t-quarter tq = wv>>1, k-group kg = wv&1)
__global__ __launch_bounds__(512, 4) void passBC(const float2* __restrict__ Xt,
                                                 float* __restrict__ ws,
                                                 const float* __restrict__ pin,
                                                 float* __restrict__ pout) {
    __shared__ float red[216 * 33];       // [value][4 tq * 8 groups + pad]
    __shared__ float VL[432];             // V[6][6][6] complex
    __shared__ float WL[72];              // W[f] rows, complex
    __shared__ float sc[16];
    const int bid = blockIdx.x;
    const int tid = threadIdx.x, wv = tid >> 6, lane = tid & 63;

    // convergence check
    {
        float d2 = 0.f, o2 = 0.f;
        for (int i = tid; i < F_DIM; i += 512) { d2 += pin[2 * i]; o2 += pin[2 * i + 1]; }
#pragma unroll
        for (int d = 1; d < 64; d <<= 1) { d2 += __shfl_xor(d2, d); o2 += __shfl_xor(o2, d); }
        if (lane == 0) { sc[wv * 2] = d2; sc[wv * 2 + 1] = o2; }
        __syncthreads();
        d2 = 0.f; o2 = 0.f;
#pragma unroll
        for (int w = 0; w < 8; ++w) { d2 += sc[w * 2]; o2 += sc[w * 2 + 1]; }
        float rel = sqrtf(d2) / fmaxf(sqrtf(o2), 1.1920929e-07f);
        __syncthreads();
        if (rel < 1e-5f) {
            if (tid == 0) { pout[2 * bid] = 0.0f; pout[2 * bid + 1] = 1.0f; }
            return;
        }
    }

    const int f  = bid;
    const int kg = wv & 1;      // k = 3*kg + j
    const int tq = wv >> 1;     // t-quarter

    float accd[3][6], accr[3][15], acci[3][15];
#pragma unroll
    for (int j = 0; j < 3; ++j) {
#pragma unroll
        for (int a = 0; a < 6; ++a) accd[j][a] = 0.f;
#pragma unroll
        for (int p = 0; p < 15; ++p) { accr[j][p] = 0.f; acci[j][p] = 0.f; }
    }
    const float2* xb = Xt + (size_t)f * 6 * T_DIM;
    const float* wt0 = ws + OFF_WT + (3 * kg) * T_DIM;
    const int tend = tq * 512 + 512;
    for (int t = tq * 512 + lane; t < tend; t += 64) {
        float g0 = wt0[t], g1 = wt0[T_DIM + t], g2 = wt0[2 * T_DIM + t];
        float2 x[6];
#pragma unroll
        for (int m = 0; m < 6; ++m) x[m] = xb[(size_t)m * T_DIM + t];
        float od[6];
#pragma unroll
        for (int a = 0; a < 6; ++a) od[a] = x[a].x * x[a].x + x[a].y * x[a].y;
        float opr[15], opi[15];
#pragma unroll
        for (int a = 1; a < 6; ++a)
#pragma unroll
            for (int b = 0; b < a; ++b) {
                const int p = a * (a - 1) / 2 + b;
                opr[p] = x[a].x * x[b].x + x[a].y * x[b].y;
                opi[p] = x[a].y * x[b].x - x[a].x * x[b].y;
            }
#pragma unroll
        for (int a = 0; a < 6; ++a) {
            accd[0][a] += g0 * od[a];
            accd[1][a] += g1 * od[a];
            accd[2][a] += g2 * od[a];
        }
#pragma unroll
        for (int p = 0; p < 15; ++p) {
            accr[0][p] += g0 * opr[p]; acci[0][p] += g0 * opi[p];
            accr[1][p] += g1 * opr[p]; acci[1][p] += g1 * opi[p];
            accr[2][p] += g2 * opr[p]; acci[2][p] += g2 * opi[p];
        }
    }
    // 8-lane pre-reduce (3 shuffle stages), 8 group slots per wave, 32 per value
#pragma unroll
    for (int j = 0; j < 3; ++j) {
#pragma unroll
        for (int a = 0; a < 6; ++a) {
            float v = accd[j][a];
            v += __shfl_xor(v, 1); v += __shfl_xor(v, 2); v += __shfl_xor(v, 4);
            if ((lane & 7) == 0)
                red[(kg * 108 + j * 36 + a) * 33 + tq * 8 + (lane >> 3)] = v;
        }
#pragma unroll
        for (int p = 0; p < 15; ++p) {
            float vr = accr[j][p];
            vr += __shfl_xor(vr, 1); vr += __shfl_xor(vr, 2); vr += __shfl_xor(vr, 4);
            float vi = acci[j][p];
            vi += __shfl_xor(vi, 1); vi += __shfl_xor(vi, 2); vi += __shfl_xor(vi, 4);
            if ((lane & 7) == 0) {
                red[(kg * 108 + j * 36 + 6 + p) * 33 + tq * 8 + (lane >> 3)]  = vr;
                red[(kg * 108 + j * 36 + 21 + p) * 33 + tq * 8 + (lane >> 3)] = vi;
            }
        }
    }
    __syncthreads();
    for (int v = tid; v < 216; v += 512) {
        float sum = 0.f;
#pragma unroll
        for (int i = 0; i < 32; ++i) sum += red[v * 33 + i];
        sum *= (1.0f / (float)T_DIM);
        int w = v / 108, rem = v % 108;
        int j = rem / 36, e = rem % 36;
        int k = 3 * w + j;
        if (e < 6) {
            VL[((k * 6 + e) * 6 + e) * 2]     = sum + 1e-6f;
            VL[((k * 6 + e) * 6 + e) * 2 + 1] = 0.f;
        } else if (e < 21) {
            int p = e - 6;
            int a = (p < 1) ? 1 : (p < 3) ? 2 : (p < 6) ? 3 : (p < 10) ? 4 : 5;
            int b = p - a * (a - 1) / 2;
            VL[((k * 6 + a) * 6 + b) * 2] = sum;
            VL[((k * 6 + b) * 6 + a) * 2] = sum;
        } else {
            int p = e - 21;
            int a = (p < 1) ? 1 : (p < 3) ? 2 : (p < 6) ? 3 : (p < 10) ? 4 : 5;
            int b = p - a * (a - 1) / 2;
            VL[((k * 6 + a) * 6 + b) * 2 + 1] =  sum;
            VL[((k * 6 + b) * 6 + a) * 2 + 1] = -sum;
        }
    }
    __syncthreads();

    // ---- ISS update: wave 0 only, wave-synchronous (no barriers) ----
    if (wv == 0) {
        float vm[36][2];
        float w6[6][2], wold[6][2];
        const int m = lane;
        if (m < 6) {
#pragma unroll
            for (int i = 0; i < 36; ++i) {
                vm[i][0] = VL[(m * 36 + i) * 2];
                vm[i][1] = VL[(m * 36 + i) * 2 + 1];
            }
            float* Wp = ws + OFF_W + ((size_t)f * 36 + m * 6) * 2;
#pragma unroll
            for (int a = 0; a < 6; ++a) {
                w6[a][0] = Wp[2 * a]; w6[a][1] = Wp[2 * a + 1];
                wold[a][0] = w6[a][0]; wold[a][1] = w6[a][1];
                WL[(m * 6 + a) * 2] = w6[a][0]; WL[(m * 6 + a) * 2 + 1] = w6[a][1];
            }
        }
        for (int k = 0; k < 6; ++k) {
            if (m < 6) {
                float wk[6][2];
#pragma unroll
                for (int a = 0; a < 6; ++a) {
                    wk[a][0] = WL[(k * 6 + a) * 2];
                    wk[a][1] = WL[(k * 6 + a) * 2 + 1];
                }
                float t6[6][2];
#pragma unroll
                for (int a = 0; a < 6; ++a) {
                    float tr = 0.f, ti = 0.f;
#pragma unroll
                    for (int b = 0; b < 6; ++b) {
                        float vr = vm[a * 6 + b][0], vi = vm[a * 6 + b][1];
                        tr += vr * wk[b][0] + vi * wk[b][1];
                        ti += vi * wk[b][0] - vr * wk[b][1];
                    }
                    t6[a][0] = tr; t6[a][1] = ti;
                }
                float quad = 0.f, nr = 0.f, ni = 0.f;
#pragma unroll
                for (int a = 0; a < 6; ++a) {
                    quad += wk[a][0] * t6[a][0] - wk[a][1] * t6[a][1];
                    nr   += w6[a][0] * t6[a][0] - w6[a][1] * t6[a][1];
                    ni   += w6[a][0] * t6[a][1] + w6[a][1] * t6[a][0];
                }
                float denom = fmaxf(quad, 1e-10f);
                float vkr, vki;
                if (m == k) { vkr = 1.0f - 1.0f / sqrtf(denom); vki = 0.0f; }
                else { float inv = 1.0f / denom; vkr = nr * inv; vki = ni * inv; }
#pragma unroll
                for (int a = 0; a < 6; ++a) {
                    w6[a][0] -= vkr * wk[a][0] - vki * wk[a][1];
                    w6[a][1] -= vkr * wk[a][1] + vki * wk[a][0];
                }
#pragma unroll
                for (int a = 0; a < 6; ++a) {
                    WL[(m * 6 + a) * 2]     = w6[a][0];
                    WL[(m * 6 + a) * 2 + 1] = w6[a][1];
                }
            }
        }
        float d2 = 0.f, o2 = 0.f;
        if (m < 6) {
            float* Wp = ws + OFF_W + ((size_t)f * 36 + m * 6) * 2;
#pragma unroll
            for (int a = 0; a < 6; ++a) {
                Wp[2 * a] = w6[a][0]; Wp[2 * a + 1] = w6[a][1];
                float dr = w6[a][0] - wold[a][0], di = w6[a][1] - wold[a][1];
                d2 += dr * dr + di * di;
                o2 += wold[a][0] * wold[a][0] + wold[a][1] * wold[a][1];
            }
        }
#pragma unroll
        for (int d = 1; d < 8; d <<= 1) {
            d2 += __shfl_xor(d2, d);
            o2 += __shfl_xor(o2, d);
        }
        if (lane == 0) {
            pout[2 * bid]     = d2;
            pout[2 * bid + 1] = o2;
        }
    }
}

// -------- final: out[k,t,f] = sum_m W[f,k,m] X[m,t,f], W cached in registers --------
__global__ __launch_bounds__(256) void finalY(const float2* __restrict__ X,
                                              const float* __restrict__ ws,
                                              float2* __restrict__ out) {
    const int f  = blockIdx.y * 256 + threadIdx.x;
    const int t0 = blockIdx.x * 16;
    if (f >= F_DIM) return;
    const float2* Wf = (const float2*)(ws + OFF_W) + (size_t)f * 36;
    float2 w[36];
#pragma unroll
    for (int i = 0; i < 36; ++i) w[i] = Wf[i];
    for (int tl = 0; tl < 16; ++tl) {
        int t = t0 + tl;
        float2 x[6];
#pragma unroll
        for (int m = 0; m < 6; ++m) x[m] = X[((size_t)m * T_DIM + t) * F_DIM + f];
#pragma unroll
        for (int k = 0; k < 6; ++k) {
            float yr = 0.f, yi = 0.f;
#pragma unroll
            for (int m = 0; m < 6; ++m) {
                float2 wk = w[k * 6 + m];
                yr += wk.x * x[m].x - wk.y * x[m].y;
                yi += wk.x * x[m].y + wk.y * x[m].x;
            }
            out[((size_t)k * T_DIM + t) * F_DIM + f] = make_float2(yr, yi);
        }
    }
}

extern "C" void kernel_launch(void* const* d_in, const int* in_sizes, int n_in,
                              void* d_out, int out_size, void* d_ws, size_t ws_size,
                              hipStream_t stream) {
    (void)in_sizes; (void)n_in; (void)out_size; (void)ws_size;
    const float2* X = (const float2*)d_in[0];
    float* ws = (float*)d_ws;
    float2* out = (float2*)d_out;
    float2* Xt = out;  // transposed X lives in d_out until finalY overwrites it

    transp<<<dim3(64, 17, 6), 256, 0, stream>>>(X, Xt, ws);
    for (int it = 0; it < N_ITER; ++it) {
        const float* pin = ws + (((it + 1) & 1) ? OFF_P1 : OFF_P0);
        float* pout      = ws + (((it    ) & 1) ? OFF_P1 : OFF_P0);
        passA<<<T_DIM / 4, 512, 0, stream>>>(X, ws, pin);
        passBC<<<F_DIM, 512, 0, stream>>>(Xt, ws, pin, pout);
    }
    finalY<<<dim3(T_DIM / 16, 3), 256, 0, stream>>>(X, ws, out);
}

// Round 5
// 948.851 us; speedup vs baseline: 2.0880x; 2.0880x over previous
//
#include <hip/hip_runtime.h>
#include <math.h>

#define T_DIM 2048
#define F_DIM 513
#define N_ITER 10

// ws float offsets
#define OFF_W    0        // 513*36*2 = 36936 floats (complex W[f][k][m])
#define OFF_WT   36936    // 6*2048   = 12288 floats
#define OFF_P0   49224    // 513*2 partial pairs (parity 0)
#define OFF_P1   50250    // 513*2 partial pairs (parity 1)

// -------- transpose X (K,T,F) -> Xt (F,K,T), + init W=I and partial buffers --------
__global__ __launch_bounds__(256) void transp(const float2* __restrict__ X,
                                              float2* __restrict__ Xt,
                                              float* __restrict__ ws) {
    const int fb  = blockIdx.x + 64 * (blockIdx.y + 17 * blockIdx.z);
    const int tid = threadIdx.x;
    if (fb < 73) {
        int idx = fb * 256 + tid;              // entry index into W (F*36 = 18468)
        if (idx < F_DIM * 36) {
            int e = idx % 36;
            ws[OFF_W + 2 * idx]     = ((e / 6) == (e % 6)) ? 1.0f : 0.0f;
            ws[OFF_W + 2 * idx + 1] = 0.0f;
        }
    } else if (fb < 78) {
        int idx = (fb - 73) * 256 + tid;       // 2*513 = 1026 floats each buffer
        if (idx < 2 * F_DIM) { ws[OFF_P0 + idx] = 1.0f; ws[OFF_P1 + idx] = 1.0f; }
    }

    __shared__ float2 tile[32][33];
    const int k  = blockIdx.z;
    const int t0 = blockIdx.x * 32;
    const int f0 = blockIdx.y * 32;
    const int tx = tid & 31, ty = tid >> 5;    // tx 0..31, ty 0..7
#pragma unroll
    for (int j = 0; j < 4; ++j) {
        int t = t0 + ty + j * 8;
        int f = f0 + tx;
        if (f < F_DIM) tile[ty + j * 8][tx] = X[((size_t)k * T_DIM + t) * F_DIM + f];
    }
    __syncthreads();
#pragma unroll
    for (int j = 0; j < 4; ++j) {
        int f = f0 + ty + j * 8;
        int t = t0 + tx;
        if (f < F_DIM) Xt[((size_t)f * 6 + k) * T_DIM + t] = tile[tx][ty + j * 8];
    }
}

// -------- pass A: wt[k,t] = 1/clip(sqrt(clip(sum_f |(W X)|^2))), 2 t's per block --------
__global__ __launch_bounds__(512) void passA(const float2* __restrict__ X,
                                             float* __restrict__ ws,
                                             const float* __restrict__ pin) {
    __shared__ float sred[96];
    const int tid = threadIdx.x, wave = tid >> 6, lane = tid & 63;

    // convergence check from previous iteration's partials (redundant per block)
    {
        float d2 = 0.f, o2 = 0.f;
        for (int i = tid; i < F_DIM; i += 512) { d2 += pin[2 * i]; o2 += pin[2 * i + 1]; }
#pragma unroll
        for (int d = 1; d < 64; d <<= 1) { d2 += __shfl_xor(d2, d); o2 += __shfl_xor(o2, d); }
        if (lane == 0) { sred[wave * 2] = d2; sred[wave * 2 + 1] = o2; }
        __syncthreads();
        d2 = 0.f; o2 = 0.f;
#pragma unroll
        for (int w = 0; w < 8; ++w) { d2 += sred[w * 2]; o2 += sred[w * 2 + 1]; }
        float rel = sqrtf(d2) / fmaxf(sqrtf(o2), 1.1920929e-07f);
        __syncthreads();
        if (rel < 1e-5f) return;
    }

    const float2* Wc = (const float2*)(ws + OFF_W);
    float* wt = ws + OFF_WT;
    const int t0 = blockIdx.x * 2;

    float s[12];
#pragma unroll
    for (int i = 0; i < 12; ++i) s[i] = 0.0f;

    for (int f = tid; f < F_DIM; f += 512) {
        float2 x[2][6];
#pragma unroll
        for (int tl = 0; tl < 2; ++tl)
#pragma unroll
            for (int m = 0; m < 6; ++m)
                x[tl][m] = X[((size_t)m * T_DIM + (t0 + tl)) * F_DIM + f];
#pragma unroll
        for (int k = 0; k < 6; ++k) {
            float2 w[6];
#pragma unroll
            for (int m = 0; m < 6; ++m) w[m] = Wc[f * 36 + k * 6 + m];
#pragma unroll
            for (int tl = 0; tl < 2; ++tl) {
                float yr = 0.f, yi = 0.f;
#pragma unroll
                for (int m = 0; m < 6; ++m) {
                    yr += w[m].x * x[tl][m].x - w[m].y * x[tl][m].y;
                    yi += w[m].x * x[tl][m].y + w[m].y * x[tl][m].x;
                }
                s[k * 2 + tl] += yr * yr + yi * yi;
            }
        }
    }
#pragma unroll
    for (int i = 0; i < 12; ++i) {
        float v = s[i];
#pragma unroll
        for (int d = 1; d < 64; d <<= 1) v += __shfl_xor(v, d);
        s[i] = v;
    }
    if (lane == 0) {
#pragma unroll
        for (int i = 0; i < 12; ++i) sred[wave * 12 + i] = s[i];
    }
    __syncthreads();
    if (tid < 12) {
        float r2 = 0.f;
#pragma unroll
        for (int w = 0; w < 8; ++w) r2 += sred[w * 12 + tid];
        int k = tid >> 1, tl = tid & 1;
        float r = sqrtf(fmaxf(r2, 1e-10f));
        wt[k * T_DIM + t0 + tl] = 1.0f / fmaxf(r, 1e-10f);
    }
}

// -------- pass B+C: V[f] in LDS, ISS update of W[f], write diff partials --------
// 6 waves: wave wv owns weight row k = wv over the full T range
__global__ __launch_bounds__(384) void passBC(const float2* __restrict__ Xt,
                                              float* __restrict__ ws,
                                              const float* __restrict__ pin,
                                              float* __restrict__ pout) {
    __shared__ float red[216 * 9];        // [6 k][36 values][8 groups + pad]
    __shared__ float VL[432];             // V[6][6][6] complex
    __shared__ float sc[12];
    const int bid = blockIdx.x;
    const int tid = threadIdx.x, wv = tid >> 6, lane = tid & 63;

    // convergence check
    {
        float d2 = 0.f, o2 = 0.f;
        for (int i = tid; i < F_DIM; i += 384) { d2 += pin[2 * i]; o2 += pin[2 * i + 1]; }
#pragma unroll
        for (int d = 1; d < 64; d <<= 1) { d2 += __shfl_xor(d2, d); o2 += __shfl_xor(o2, d); }
        if (lane == 0) { sc[wv * 2] = d2; sc[wv * 2 + 1] = o2; }
        __syncthreads();
        d2 = 0.f; o2 = 0.f;
#pragma unroll
        for (int w = 0; w < 6; ++w) { d2 += sc[w * 2]; o2 += sc[w * 2 + 1]; }
        float rel = sqrtf(d2) / fmaxf(sqrtf(o2), 1.1920929e-07f);
        __syncthreads();
        if (rel < 1e-5f) {
            if (tid == 0) { pout[2 * bid] = 0.0f; pout[2 * bid + 1] = 1.0f; }
            return;
        }
    }

    const int f = bid;
    const int k = wv;

    float accd[6], accr[15], acci[15];
#pragma unroll
    for (int a = 0; a < 6; ++a) accd[a] = 0.f;
#pragma unroll
    for (int p = 0; p < 15; ++p) { accr[p] = 0.f; acci[p] = 0.f; }

    const float2* xb  = Xt + (size_t)f * 6 * T_DIM;
    const float* wtk = ws + OFF_WT + k * T_DIM;
    for (int t = lane; t < T_DIM; t += 64) {
        float g = wtk[t];
        float2 x[6];
#pragma unroll
        for (int m = 0; m < 6; ++m) x[m] = xb[(size_t)m * T_DIM + t];
#pragma unroll
        for (int a = 0; a < 6; ++a)
            accd[a] = fmaf(g, x[a].x * x[a].x + x[a].y * x[a].y, accd[a]);
#pragma unroll
        for (int a = 1; a < 6; ++a)
#pragma unroll
            for (int b = 0; b < a; ++b) {
                const int p = a * (a - 1) / 2 + b;
                accr[p] = fmaf(g, x[a].x * x[b].x + x[a].y * x[b].y, accr[p]);
                acci[p] = fmaf(g, x[a].y * x[b].x - x[a].x * x[b].y, acci[p]);
            }
    }
    // 8-lane pre-reduce (3 shuffle stages), 8 group slots per value
#pragma unroll
    for (int a = 0; a < 6; ++a) {
        float v = accd[a];
        v += __shfl_xor(v, 1); v += __shfl_xor(v, 2); v += __shfl_xor(v, 4);
        if ((lane & 7) == 0) red[(k * 36 + a) * 9 + (lane >> 3)] = v;
    }
#pragma unroll
    for (int p = 0; p < 15; ++p) {
        float vr = accr[p];
        vr += __shfl_xor(vr, 1); vr += __shfl_xor(vr, 2); vr += __shfl_xor(vr, 4);
        float vi = acci[p];
        vi += __shfl_xor(vi, 1); vi += __shfl_xor(vi, 2); vi += __shfl_xor(vi, 4);
        if ((lane & 7) == 0) {
            red[(k * 36 + 6 + p) * 9 + (lane >> 3)]  = vr;
            red[(k * 36 + 21 + p) * 9 + (lane >> 3)] = vi;
        }
    }
    __syncthreads();
    for (int v = tid; v < 216; v += 384) {
        float sum = 0.f;
#pragma unroll
        for (int i = 0; i < 8; ++i) sum += red[v * 9 + i];
        sum *= (1.0f / (float)T_DIM);
        int kk = v / 36, e = v % 36;
        if (e < 6) {
            VL[((kk * 6 + e) * 6 + e) * 2]     = sum + 1e-6f;
            VL[((kk * 6 + e) * 6 + e) * 2 + 1] = 0.f;
        } else if (e < 21) {
            int p = e - 6;
            int a = (p < 1) ? 1 : (p < 3) ? 2 : (p < 6) ? 3 : (p < 10) ? 4 : 5;
            int b = p - a * (a - 1) / 2;
            VL[((kk * 6 + a) * 6 + b) * 2] = sum;
            VL[((kk * 6 + b) * 6 + a) * 2] = sum;
        } else {
            int p = e - 21;
            int a = (p < 1) ? 1 : (p < 3) ? 2 : (p < 6) ? 3 : (p < 10) ? 4 : 5;
            int b = p - a * (a - 1) / 2;
            VL[((kk * 6 + a) * 6 + b) * 2 + 1] =  sum;
            VL[((kk * 6 + b) * 6 + a) * 2 + 1] = -sum;
        }
    }
    __syncthreads();

    // ---- ISS update: wave 0 only, wave-synchronous; V read from LDS, wk via shuffle ----
    if (wv == 0) {
        const int m = lane;
        const bool act = (m < 6);
        float w6[6][2], wold[6][2];
#pragma unroll
        for (int a = 0; a < 6; ++a) {
            w6[a][0] = 0.f; w6[a][1] = 0.f; wold[a][0] = 0.f; wold[a][1] = 0.f;
        }
        float* Wp = ws + OFF_W + ((size_t)f * 36 + (act ? m : 0) * 6) * 2;
        if (act) {
#pragma unroll
            for (int a = 0; a < 6; ++a) {
                w6[a][0] = Wp[2 * a]; w6[a][1] = Wp[2 * a + 1];
                wold[a][0] = w6[a][0]; wold[a][1] = w6[a][1];
            }
        }
        const float2* VL2 = (const float2*)VL;
        for (int kk = 0; kk < 6; ++kk) {
            float wk[6][2];
#pragma unroll
            for (int a = 0; a < 6; ++a) {
                wk[a][0] = __shfl(w6[a][0], kk);
                wk[a][1] = __shfl(w6[a][1], kk);
            }
            if (act) {
                float t6[6][2];
#pragma unroll
                for (int a = 0; a < 6; ++a) {
                    float tr = 0.f, ti = 0.f;
#pragma unroll
                    for (int b = 0; b < 6; ++b) {
                        float2 vv = VL2[m * 36 + a * 6 + b];
                        tr += vv.x * wk[b][0] + vv.y * wk[b][1];
                        ti += vv.y * wk[b][0] - vv.x * wk[b][1];
                    }
                    t6[a][0] = tr; t6[a][1] = ti;
                }
                float quad = 0.f, nr = 0.f, ni = 0.f;
#pragma unroll
                for (int a = 0; a < 6; ++a) {
                    quad += wk[a][0] * t6[a][0] - wk[a][1] * t6[a][1];
                    nr   += w6[a][0] * t6[a][0] - w6[a][1] * t6[a][1];
                    ni   += w6[a][0] * t6[a][1] + w6[a][1] * t6[a][0];
                }
                float denom = fmaxf(quad, 1e-10f);
                float vkr, vki;
                if (m == kk) { vkr = 1.0f - 1.0f / sqrtf(denom); vki = 0.0f; }
                else { float inv = 1.0f / denom; vkr = nr * inv; vki = ni * inv; }
#pragma unroll
                for (int a = 0; a < 6; ++a) {
                    w6[a][0] -= vkr * wk[a][0] - vki * wk[a][1];
                    w6[a][1] -= vkr * wk[a][1] + vki * wk[a][0];
                }
            }
        }
        float d2 = 0.f, o2 = 0.f;
        if (act) {
#pragma unroll
            for (int a = 0; a < 6; ++a) {
                Wp[2 * a] = w6[a][0]; Wp[2 * a + 1] = w6[a][1];
                float dr = w6[a][0] - wold[a][0], di = w6[a][1] - wold[a][1];
                d2 += dr * dr + di * di;
                o2 += wold[a][0] * wold[a][0] + wold[a][1] * wold[a][1];
            }
        }
#pragma unroll
        for (int d = 1; d < 8; d <<= 1) {
            d2 += __shfl_xor(d2, d);
            o2 += __shfl_xor(o2, d);
        }
        if (lane == 0) {
            pout[2 * bid]     = d2;
            pout[2 * bid + 1] = o2;
        }
    }
}

// -------- final: out[k,t,f] = sum_m W[f,k,m] X[m,t,f], W cached in registers --------
__global__ __launch_bounds__(256) void finalY(const float2* __restrict__ X,
                                              const float* __restrict__ ws,
                                              float2* __restrict__ out) {
    const int f  = blockIdx.y * 256 + threadIdx.x;
    const int t0 = blockIdx.x * 16;
    if (f >= F_DIM) return;
    const float2* Wf = (const float2*)(ws + OFF_W) + (size_t)f * 36;
    float2 w[36];
#pragma unroll
    for (int i = 0; i < 36; ++i) w[i] = Wf[i];
    for (int tl = 0; tl < 16; ++tl) {
        int t = t0 + tl;
        float2 x[6];
#pragma unroll
        for (int m = 0; m < 6; ++m) x[m] = X[((size_t)m * T_DIM + t) * F_DIM + f];
#pragma unroll
        for (int k = 0; k < 6; ++k) {
            float yr = 0.f, yi = 0.f;
#pragma unroll
            for (int m = 0; m < 6; ++m) {
                float2 wk = w[k * 6 + m];
                yr += wk.x * x[m].x - wk.y * x[m].y;
                yi += wk.x * x[m].y + wk.y * x[m].x;
            }
            out[((size_t)k * T_DIM + t) * F_DIM + f] = make_float2(yr, yi);
        }
    }
}

extern "C" void kernel_launch(void* const* d_in, const int* in_sizes, int n_in,
                              void* d_out, int out_size, void* d_ws, size_t ws_size,
                              hipStream_t stream) {
    (void)in_sizes; (void)n_in; (void)out_size; (void)ws_size;
    const float2* X = (const float2*)d_in[0];
    float* ws = (float*)d_ws;
    float2* out = (float2*)d_out;
    float2* Xt = out;  // transposed X lives in d_out until finalY overwrites it

    transp<<<dim3(64, 17, 6), 256, 0, stream>>>(X, Xt, ws);
    for (int it = 0; it < N_ITER; ++it) {
        const float* pin = ws + (((it + 1) & 1) ? OFF_P1 : OFF_P0);
        float* pout      = ws + (((it    ) & 1) ? OFF_P1 : OFF_P0);
        passA<<<T_DIM / 2, 512, 0, stream>>>(X, ws, pin);
        passBC<<<F_DIM, 384, 0, stream>>>(Xt, ws, pin, pout);
    }
    finalY<<<dim3(T_DIM / 16, 3), 256, 0, stream>>>(X, ws, out);
}

// Round 6
// 937.141 us; speedup vs baseline: 2.1141x; 1.0125x over previous
//
#include <hip/hip_runtime.h>
#include <math.h>

#define T_DIM 2048
#define F_DIM 513
#define N_ITER 10

// ws float offsets
#define OFF_W    0        // 513*36*2 = 36936 floats (complex W[f][k][m])
#define OFF_WT   36936    // 6*2048   = 12288 floats
#define OFF_P0   49224    // 513*2 partial pairs (parity 0)
#define OFF_P1   50250    // 513*2 partial pairs (parity 1)
#define OFF_R2   51276    // 17*6*2048 = 208896 floats (r2 partials per f-chunk)
#define OFF_VP   51276    // 513*4*216 = 443232 floats (V partials) -- time-shared with R2

// -------- transpose X (K,T,F) -> Xt (F,K,T), + init W=I and partial buffers --------
__global__ __launch_bounds__(256) void transp(const float2* __restrict__ X,
                                              float2* __restrict__ Xt,
                                              float* __restrict__ ws) {
    const int fb  = blockIdx.x + 64 * (blockIdx.y + 17 * blockIdx.z);
    const int tid = threadIdx.x;
    if (fb < 73) {
        int idx = fb * 256 + tid;              // entry index into W (F*36 = 18468)
        if (idx < F_DIM * 36) {
            int e = idx % 36;
            ws[OFF_W + 2 * idx]     = ((e / 6) == (e % 6)) ? 1.0f : 0.0f;
            ws[OFF_W + 2 * idx + 1] = 0.0f;
        }
    } else if (fb < 78) {
        int idx = (fb - 73) * 256 + tid;       // 2*513 = 1026 floats each buffer
        if (idx < 2 * F_DIM) { ws[OFF_P0 + idx] = 1.0f; ws[OFF_P1 + idx] = 1.0f; }
    }

    __shared__ float2 tile[32][33];
    const int k  = blockIdx.z;
    const int t0 = blockIdx.x * 32;
    const int f0 = blockIdx.y * 32;
    const int tx = tid & 31, ty = tid >> 5;    // tx 0..31, ty 0..7
#pragma unroll
    for (int j = 0; j < 4; ++j) {
        int t = t0 + ty + j * 8;
        int f = f0 + tx;
        if (f < F_DIM) tile[ty + j * 8][tx] = X[((size_t)k * T_DIM + t) * F_DIM + f];
    }
    __syncthreads();
#pragma unroll
    for (int j = 0; j < 4; ++j) {
        int f = f0 + ty + j * 8;
        int t = t0 + tx;
        if (f < F_DIM) Xt[((size_t)f * 6 + k) * T_DIM + t] = tile[tx][ty + j * 8];
    }
}

// -------- pass A1: r2 partials. block=(t-chunk of 64, f-chunk of 32), lanes over t --------
__global__ __launch_bounds__(256) void passA1(const float2* __restrict__ Xt,
                                              float* __restrict__ ws,
                                              const float* __restrict__ pin) {
    __shared__ float r2s[4][6][65];
    __shared__ float sc[8];
    const int tid = threadIdx.x, wv = tid >> 6, lane = tid & 63;
    {
        float d2 = 0.f, o2 = 0.f;
        for (int i = tid; i < F_DIM; i += 256) { d2 += pin[2 * i]; o2 += pin[2 * i + 1]; }
#pragma unroll
        for (int d = 1; d < 64; d <<= 1) { d2 += __shfl_xor(d2, d); o2 += __shfl_xor(o2, d); }
        if (lane == 0) { sc[wv * 2] = d2; sc[wv * 2 + 1] = o2; }
        __syncthreads();
        d2 = sc[0] + sc[2] + sc[4] + sc[6];
        o2 = sc[1] + sc[3] + sc[5] + sc[7];
        float rel = sqrtf(d2) / fmaxf(sqrtf(o2), 1.1920929e-07f);
        if (rel < 1e-5f) return;
    }
    const int t  = blockIdx.x * 64 + lane;
    const int fc = blockIdx.y;
    const float2* Wc = (const float2*)(ws + OFF_W);
    float acc[6] = {0.f, 0.f, 0.f, 0.f, 0.f, 0.f};
#pragma unroll
    for (int i = 0; i < 8; ++i) {
        const int f = fc * 32 + wv * 8 + i;
        if (f < F_DIM) {
            const float2* xf = Xt + (size_t)f * 6 * T_DIM + t;
            float2 x[6];
#pragma unroll
            for (int m = 0; m < 6; ++m) x[m] = xf[(size_t)m * T_DIM];
            const float2* wf = Wc + f * 36;
#pragma unroll
            for (int k = 0; k < 6; ++k) {
                float yr = 0.f, yi = 0.f;
#pragma unroll
                for (int m = 0; m < 6; ++m) {
                    float2 wk = wf[k * 6 + m];
                    yr += wk.x * x[m].x - wk.y * x[m].y;
                    yi += wk.x * x[m].y + wk.y * x[m].x;
                }
                acc[k] += yr * yr + yi * yi;
            }
        }
    }
#pragma unroll
    for (int k = 0; k < 6; ++k) r2s[wv][k][lane] = acc[k];
    __syncthreads();
    for (int v = tid; v < 384; v += 256) {
        int k = v >> 6, l = v & 63;
        float s = r2s[0][k][l] + r2s[1][k][l] + r2s[2][k][l] + r2s[3][k][l];
        ws[OFF_R2 + ((size_t)fc * 6 + k) * T_DIM + blockIdx.x * 64 + l] = s;
    }
}

// -------- pass A2: wt[k,t] = 1/clip(sqrt(clip(sum_fc r2part))) --------
__global__ __launch_bounds__(256) void passA2(float* __restrict__ ws,
                                              const float* __restrict__ pin) {
    __shared__ float sc[8];
    const int tid = threadIdx.x, wv = tid >> 6, lane = tid & 63;
    {
        float d2 = 0.f, o2 = 0.f;
        for (int i = tid; i < F_DIM; i += 256) { d2 += pin[2 * i]; o2 += pin[2 * i + 1]; }
#pragma unroll
        for (int d = 1; d < 64; d <<= 1) { d2 += __shfl_xor(d2, d); o2 += __shfl_xor(o2, d); }
        if (lane == 0) { sc[wv * 2] = d2; sc[wv * 2 + 1] = o2; }
        __syncthreads();
        d2 = sc[0] + sc[2] + sc[4] + sc[6];
        o2 = sc[1] + sc[3] + sc[5] + sc[7];
        float rel = sqrtf(d2) / fmaxf(sqrtf(o2), 1.1920929e-07f);
        if (rel < 1e-5f) return;
    }
    const int idx = blockIdx.x * 256 + tid;    // = k*T_DIM + t
    float s = 0.f;
#pragma unroll
    for (int fc = 0; fc < 17; ++fc) s += ws[OFF_R2 + (size_t)fc * 6 * T_DIM + idx];
    float r = sqrtf(fmaxf(s, 1e-10f));
    ws[OFF_WT + idx] = 1.0f / fmaxf(r, 1e-10f);
}

// -------- pass B partial: V partials per (f, t-quarter). waves=(kg,ts), 3 k's/wave --------
__global__ __launch_bounds__(256) void passBpart(const float2* __restrict__ Xt,
                                                 float* __restrict__ ws,
                                                 const float* __restrict__ pin) {
    __shared__ float red[216 * 17];
    __shared__ float sc[8];
    const int tid = threadIdx.x, wv = tid >> 6, lane = tid & 63;
    const int kg = wv & 1, ts = wv >> 1;
    {
        float d2 = 0.f, o2 = 0.f;
        for (int i = tid; i < F_DIM; i += 256) { d2 += pin[2 * i]; o2 += pin[2 * i + 1]; }
#pragma unroll
        for (int d = 1; d < 64; d <<= 1) { d2 += __shfl_xor(d2, d); o2 += __shfl_xor(o2, d); }
        if (lane == 0) { sc[wv * 2] = d2; sc[wv * 2 + 1] = o2; }
        __syncthreads();
        d2 = sc[0] + sc[2] + sc[4] + sc[6];
        o2 = sc[1] + sc[3] + sc[5] + sc[7];
        float rel = sqrtf(d2) / fmaxf(sqrtf(o2), 1.1920929e-07f);
        if (rel < 1e-5f) return;
    }
    const int f = blockIdx.x, tq = blockIdx.y;

    float accd[3][6], accr[3][15], acci[3][15];
#pragma unroll
    for (int j = 0; j < 3; ++j) {
#pragma unroll
        for (int a = 0; a < 6; ++a) accd[j][a] = 0.f;
#pragma unroll
        for (int p = 0; p < 15; ++p) { accr[j][p] = 0.f; acci[j][p] = 0.f; }
    }
    const float2* xb = Xt + (size_t)f * 6 * T_DIM;
    const float* wt0 = ws + OFF_WT + (3 * kg) * T_DIM;
    const int tbase = tq * 512 + ts * 256 + lane;
#pragma unroll
    for (int i = 0; i < 4; ++i) {
        const int t = tbase + i * 64;
        float g0 = wt0[t], g1 = wt0[T_DIM + t], g2 = wt0[2 * T_DIM + t];
        float2 x[6];
#pragma unroll
        for (int m = 0; m < 6; ++m) x[m] = xb[(size_t)m * T_DIM + t];
        float od[6], opr[15], opi[15];
#pragma unroll
        for (int a = 0; a < 6; ++a) od[a] = x[a].x * x[a].x + x[a].y * x[a].y;
#pragma unroll
        for (int a = 1; a < 6; ++a)
#pragma unroll
            for (int b = 0; b < a; ++b) {
                const int p = a * (a - 1) / 2 + b;
                opr[p] = x[a].x * x[b].x + x[a].y * x[b].y;
                opi[p] = x[a].y * x[b].x - x[a].x * x[b].y;
            }
#pragma unroll
        for (int a = 0; a < 6; ++a) {
            accd[0][a] = fmaf(g0, od[a], accd[0][a]);
            accd[1][a] = fmaf(g1, od[a], accd[1][a]);
            accd[2][a] = fmaf(g2, od[a], accd[2][a]);
        }
#pragma unroll
        for (int p = 0; p < 15; ++p) {
            accr[0][p] = fmaf(g0, opr[p], accr[0][p]);  acci[0][p] = fmaf(g0, opi[p], acci[0][p]);
            accr[1][p] = fmaf(g1, opr[p], accr[1][p]);  acci[1][p] = fmaf(g1, opi[p], acci[1][p]);
            accr[2][p] = fmaf(g2, opr[p], accr[2][p]);  acci[2][p] = fmaf(g2, opi[p], acci[2][p]);
        }
    }
    // 8-lane pre-reduce (3 shuffle stages); 16 slots per value (2 ts-waves x 8 groups)
#pragma unroll
    for (int j = 0; j < 3; ++j) {
#pragma unroll
        for (int a = 0; a < 6; ++a) {
            float v = accd[j][a];
            v += __shfl_xor(v, 1); v += __shfl_xor(v, 2); v += __shfl_xor(v, 4);
            if ((lane & 7) == 0)
                red[(kg * 108 + j * 36 + a) * 17 + ts * 8 + (lane >> 3)] = v;
        }
#pragma unroll
        for (int p = 0; p < 15; ++p) {
            float vr = accr[j][p];
            vr += __shfl_xor(vr, 1); vr += __shfl_xor(vr, 2); vr += __shfl_xor(vr, 4);
            float vi = acci[j][p];
            vi += __shfl_xor(vi, 1); vi += __shfl_xor(vi, 2); vi += __shfl_xor(vi, 4);
            if ((lane & 7) == 0) {
                red[(kg * 108 + j * 36 + 6 + p) * 17 + ts * 8 + (lane >> 3)]  = vr;
                red[(kg * 108 + j * 36 + 21 + p) * 17 + ts * 8 + (lane >> 3)] = vi;
            }
        }
    }
    __syncthreads();
    for (int v = tid; v < 216; v += 256) {
        float sum = 0.f;
#pragma unroll
        for (int i = 0; i < 16; ++i) sum += red[v * 17 + i];
        ws[OFF_VP + ((size_t)f * 4 + tq) * 216 + v] = sum;
    }
}

// -------- pass C: sum V partials, build V in LDS, wave-synchronous ISS update --------
__global__ __launch_bounds__(64) void passC(float* __restrict__ ws,
                                            const float* __restrict__ pin,
                                            float* __restrict__ pout) {
    __shared__ float VL[432];
    const int f = blockIdx.x;
    const int lane = threadIdx.x;
    {
        float d2 = 0.f, o2 = 0.f;
        for (int i = lane; i < F_DIM; i += 64) { d2 += pin[2 * i]; o2 += pin[2 * i + 1]; }
#pragma unroll
        for (int d = 1; d < 64; d <<= 1) { d2 += __shfl_xor(d2, d); o2 += __shfl_xor(o2, d); }
        float rel = sqrtf(d2) / fmaxf(sqrtf(o2), 1.1920929e-07f);
        if (rel < 1e-5f) {
            if (lane == 0) { pout[2 * f] = 0.0f; pout[2 * f + 1] = 1.0f; }
            return;
        }
    }
    for (int v = lane; v < 216; v += 64) {
        float sum = 0.f;
#pragma unroll
        for (int tq = 0; tq < 4; ++tq)
            sum += ws[OFF_VP + ((size_t)f * 4 + tq) * 216 + v];
        sum *= (1.0f / (float)T_DIM);
        int kk = v / 36, e = v % 36;
        if (e < 6) {
            VL[((kk * 6 + e) * 6 + e) * 2]     = sum + 1e-6f;
            VL[((kk * 6 + e) * 6 + e) * 2 + 1] = 0.f;
        } else if (e < 21) {
            int p = e - 6;
            int a = (p < 1) ? 1 : (p < 3) ? 2 : (p < 6) ? 3 : (p < 10) ? 4 : 5;
            int b = p - a * (a - 1) / 2;
            VL[((kk * 6 + a) * 6 + b) * 2] = sum;
            VL[((kk * 6 + b) * 6 + a) * 2] = sum;
        } else {
            int p = e - 21;
            int a = (p < 1) ? 1 : (p < 3) ? 2 : (p < 6) ? 3 : (p < 10) ? 4 : 5;
            int b = p - a * (a - 1) / 2;
            VL[((kk * 6 + a) * 6 + b) * 2 + 1] =  sum;
            VL[((kk * 6 + b) * 6 + a) * 2 + 1] = -sum;
        }
    }
    __syncthreads();

    const int m = lane;
    const bool act = (m < 6);
    float w6[6][2], wold[6][2];
#pragma unroll
    for (int a = 0; a < 6; ++a) {
        w6[a][0] = 0.f; w6[a][1] = 0.f; wold[a][0] = 0.f; wold[a][1] = 0.f;
    }
    float* Wp = ws + OFF_W + ((size_t)f * 36 + (act ? m : 0) * 6) * 2;
    if (act) {
#pragma unroll
        for (int a = 0; a < 6; ++a) {
            w6[a][0] = Wp[2 * a]; w6[a][1] = Wp[2 * a + 1];
            wold[a][0] = w6[a][0]; wold[a][1] = w6[a][1];
        }
    }
    const float2* VL2 = (const float2*)VL;
    for (int kk = 0; kk < 6; ++kk) {
        float wk[6][2];
#pragma unroll
        for (int a = 0; a < 6; ++a) {
            wk[a][0] = __shfl(w6[a][0], kk);
            wk[a][1] = __shfl(w6[a][1], kk);
        }
        if (act) {
            float t6[6][2];
#pragma unroll
            for (int a = 0; a < 6; ++a) {
                float tr = 0.f, ti = 0.f;
#pragma unroll
                for (int b = 0; b < 6; ++b) {
                    float2 vv = VL2[m * 36 + a * 6 + b];
                    tr += vv.x * wk[b][0] + vv.y * wk[b][1];
                    ti += vv.y * wk[b][0] - vv.x * wk[b][1];
                }
                t6[a][0] = tr; t6[a][1] = ti;
            }
            float quad = 0.f, nr = 0.f, ni = 0.f;
#pragma unroll
            for (int a = 0; a < 6; ++a) {
                quad += wk[a][0] * t6[a][0] - wk[a][1] * t6[a][1];
                nr   += w6[a][0] * t6[a][0] - w6[a][1] * t6[a][1];
                ni   += w6[a][0] * t6[a][1] + w6[a][1] * t6[a][0];
            }
            float denom = fmaxf(quad, 1e-10f);
            float vkr, vki;
            if (m == kk) { vkr = 1.0f - 1.0f / sqrtf(denom); vki = 0.0f; }
            else { float inv = 1.0f / denom; vkr = nr * inv; vki = ni * inv; }
#pragma unroll
            for (int a = 0; a < 6; ++a) {
                w6[a][0] -= vkr * wk[a][0] - vki * wk[a][1];
                w6[a][1] -= vkr * wk[a][1] + vki * wk[a][0];
            }
        }
    }
    float d2 = 0.f, o2 = 0.f;
    if (act) {
#pragma unroll
        for (int a = 0; a < 6; ++a) {
            Wp[2 * a] = w6[a][0]; Wp[2 * a + 1] = w6[a][1];
            float dr = w6[a][0] - wold[a][0], di = w6[a][1] - wold[a][1];
            d2 += dr * dr + di * di;
            o2 += wold[a][0] * wold[a][0] + wold[a][1] * wold[a][1];
        }
    }
#pragma unroll
    for (int d = 1; d < 8; d <<= 1) {
        d2 += __shfl_xor(d2, d);
        o2 += __shfl_xor(o2, d);
    }
    if (lane == 0) {
        pout[2 * f]     = d2;
        pout[2 * f + 1] = o2;
    }
}

// -------- final: out[k,t,f] = sum_m W[f,k,m] X[m,t,f], W cached in registers --------
__global__ __launch_bounds__(256) void finalY(const float2* __restrict__ X,
                                              const float* __restrict__ ws,
                                              float2* __restrict__ out) {
    const int f  = blockIdx.y * 256 + threadIdx.x;
    const int t0 = blockIdx.x * 4;
    if (f >= F_DIM) return;
    const float2* Wf = (const float2*)(ws + OFF_W) + (size_t)f * 36;
    float2 w[36];
#pragma unroll
    for (int i = 0; i < 36; ++i) w[i] = Wf[i];
#pragma unroll
    for (int tl = 0; tl < 4; ++tl) {
        int t = t0 + tl;
        float2 x[6];
#pragma unroll
        for (int m = 0; m < 6; ++m) x[m] = X[((size_t)m * T_DIM + t) * F_DIM + f];
#pragma unroll
        for (int k = 0; k < 6; ++k) {
            float yr = 0.f, yi = 0.f;
#pragma unroll
            for (int m = 0; m < 6; ++m) {
                float2 wk = w[k * 6 + m];
                yr += wk.x * x[m].x - wk.y * x[m].y;
                yi += wk.x * x[m].y + wk.y * x[m].x;
            }
            out[((size_t)k * T_DIM + t) * F_DIM + f] = make_float2(yr, yi);
        }
    }
}

extern "C" void kernel_launch(void* const* d_in, const int* in_sizes, int n_in,
                              void* d_out, int out_size, void* d_ws, size_t ws_size,
                              hipStream_t stream) {
    (void)in_sizes; (void)n_in; (void)out_size; (void)ws_size;
    const float2* X = (const float2*)d_in[0];
    float* ws = (float*)d_ws;
    float2* out = (float2*)d_out;
    float2* Xt = out;  // transposed X lives in d_out until finalY overwrites it

    transp<<<dim3(64, 17, 6), 256, 0, stream>>>(X, Xt, ws);
    for (int it = 0; it < N_ITER; ++it) {
        const float* pin = ws + (((it + 1) & 1) ? OFF_P1 : OFF_P0);
        float* pout      = ws + (((it    ) & 1) ? OFF_P1 : OFF_P0);
        passA1<<<dim3(32, 17), 256, 0, stream>>>(Xt, ws, pin);
        passA2<<<48, 256, 0, stream>>>(ws, pin);
        passBpart<<<dim3(F_DIM, 4), 256, 0, stream>>>(Xt, ws, pin);
        passC<<<F_DIM, 64, 0, stream>>>(ws, pin, pout);
    }
    finalY<<<dim3(T_DIM / 4, 3), 256, 0, stream>>>(X, ws, out);
}

// Round 7
// 803.740 us; speedup vs baseline: 2.4650x; 1.1660x over previous
//
#include <hip/hip_runtime.h>
#include <hip/hip_bf16.h>
#include <math.h>

#define T_DIM 2048
#define F_DIM 513
#define N_ITER 10

// ws float offsets
#define OFF_W    0        // 513*36*2 = 36936 floats (complex W[f][k][m])
#define OFF_WT   36936    // 6*2048   = 12288 floats
#define OFF_P0   49224    // 513*2 partial pairs (parity 0)
#define OFF_P1   50250    // 513*2 partial pairs (parity 1)
#define OFF_R2   51276    // 17*6*2048 floats (r2 partials per f-chunk)

typedef __attribute__((ext_vector_type(8))) short bf16x8;
typedef __attribute__((ext_vector_type(4))) float f32x4;

static __device__ inline unsigned pack2bf(float a, float b) {
    union { __hip_bfloat16 h; unsigned short u; } ca, cb;
    ca.h = __float2bfloat16(a);
    cb.h = __float2bfloat16(b);
    return (unsigned)ca.u | ((unsigned)cb.u << 16);
}

// -------- transpose X (K,T,F) -> Xt (F,K,T), + init W=I and partial buffers --------
__global__ __launch_bounds__(256) void transp(const float2* __restrict__ X,
                                              float2* __restrict__ Xt,
                                              float* __restrict__ ws) {
    const int fb  = blockIdx.x + 64 * (blockIdx.y + 17 * blockIdx.z);
    const int tid = threadIdx.x;
    if (fb < 73) {
        int idx = fb * 256 + tid;
        if (idx < F_DIM * 36) {
            int e = idx % 36;
            ws[OFF_W + 2 * idx]     = ((e / 6) == (e % 6)) ? 1.0f : 0.0f;
            ws[OFF_W + 2 * idx + 1] = 0.0f;
        }
    } else if (fb < 78) {
        int idx = (fb - 73) * 256 + tid;
        if (idx < 2 * F_DIM) { ws[OFF_P0 + idx] = 1.0f; ws[OFF_P1 + idx] = 1.0f; }
    }

    __shared__ float2 tile[32][33];
    const int k  = blockIdx.z;
    const int t0 = blockIdx.x * 32;
    const int f0 = blockIdx.y * 32;
    const int tx = tid & 31, ty = tid >> 5;
#pragma unroll
    for (int j = 0; j < 4; ++j) {
        int t = t0 + ty + j * 8;
        int f = f0 + tx;
        if (f < F_DIM) tile[ty + j * 8][tx] = X[((size_t)k * T_DIM + t) * F_DIM + f];
    }
    __syncthreads();
#pragma unroll
    for (int j = 0; j < 4; ++j) {
        int f = f0 + ty + j * 8;
        int t = t0 + tx;
        if (f < F_DIM) Xt[((size_t)f * 6 + k) * T_DIM + t] = tile[tx][ty + j * 8];
    }
}

// -------- pass A1: r2 partials. block=(t-chunk of 64, f-chunk of 32), lanes over t --------
__global__ __launch_bounds__(256) void passA1(const float2* __restrict__ Xt,
                                              float* __restrict__ ws,
                                              const float* __restrict__ pin) {
    __shared__ float r2s[4][6][65];
    __shared__ float sc[8];
    const int tid = threadIdx.x, wv = tid >> 6, lane = tid & 63;
    {
        float d2 = 0.f, o2 = 0.f;
        for (int i = tid; i < F_DIM; i += 256) { d2 += pin[2 * i]; o2 += pin[2 * i + 1]; }
#pragma unroll
        for (int d = 1; d < 64; d <<= 1) { d2 += __shfl_xor(d2, d); o2 += __shfl_xor(o2, d); }
        if (lane == 0) { sc[wv * 2] = d2; sc[wv * 2 + 1] = o2; }
        __syncthreads();
        d2 = sc[0] + sc[2] + sc[4] + sc[6];
        o2 = sc[1] + sc[3] + sc[5] + sc[7];
        float rel = sqrtf(d2) / fmaxf(sqrtf(o2), 1.1920929e-07f);
        if (rel < 1e-5f) return;
    }
    const int t  = blockIdx.x * 64 + lane;
    const int fc = blockIdx.y;
    const float2* Wc = (const float2*)(ws + OFF_W);
    float acc[6] = {0.f, 0.f, 0.f, 0.f, 0.f, 0.f};
#pragma unroll
    for (int i = 0; i < 8; ++i) {
        const int f = fc * 32 + wv * 8 + i;
        if (f < F_DIM) {
            const float2* xf = Xt + (size_t)f * 6 * T_DIM + t;
            float2 x[6];
#pragma unroll
            for (int m = 0; m < 6; ++m) x[m] = xf[(size_t)m * T_DIM];
            const float2* wf = Wc + f * 36;
#pragma unroll
            for (int k = 0; k < 6; ++k) {
                float yr = 0.f, yi = 0.f;
#pragma unroll
                for (int m = 0; m < 6; ++m) {
                    float2 wk = wf[k * 6 + m];
                    yr += wk.x * x[m].x - wk.y * x[m].y;
                    yi += wk.x * x[m].y + wk.y * x[m].x;
                }
                acc[k] += yr * yr + yi * yi;
            }
        }
    }
#pragma unroll
    for (int k = 0; k < 6; ++k) r2s[wv][k][lane] = acc[k];
    __syncthreads();
    for (int v = tid; v < 384; v += 256) {
        int k = v >> 6, l = v & 63;
        float s = r2s[0][k][l] + r2s[1][k][l] + r2s[2][k][l] + r2s[3][k][l];
        ws[OFF_R2 + ((size_t)fc * 6 + k) * T_DIM + blockIdx.x * 64 + l] = s;
    }
}

// -------- pass A2: wt[k,t] = 1/clip(sqrt(clip(sum_fc r2part))) --------
__global__ __launch_bounds__(256) void passA2(float* __restrict__ ws,
                                              const float* __restrict__ pin) {
    __shared__ float sc[8];
    const int tid = threadIdx.x, wv = tid >> 6, lane = tid & 63;
    {
        float d2 = 0.f, o2 = 0.f;
        for (int i = tid; i < F_DIM; i += 256) { d2 += pin[2 * i]; o2 += pin[2 * i + 1]; }
#pragma unroll
        for (int d = 1; d < 64; d <<= 1) { d2 += __shfl_xor(d2, d); o2 += __shfl_xor(o2, d); }
        if (lane == 0) { sc[wv * 2] = d2; sc[wv * 2 + 1] = o2; }
        __syncthreads();
        d2 = sc[0] + sc[2] + sc[4] + sc[6];
        o2 = sc[1] + sc[3] + sc[5] + sc[7];
        float rel = sqrtf(d2) / fmaxf(sqrtf(o2), 1.1920929e-07f);
        if (rel < 1e-5f) return;
    }
    const int idx = blockIdx.x * 256 + tid;    // = k*T_DIM + t
    float s = 0.f;
#pragma unroll
    for (int fc = 0; fc < 17; ++fc) s += ws[OFF_R2 + (size_t)fc * 6 * T_DIM + idx];
    float r = sqrtf(fmaxf(s, 1e-10f));
    ws[OFF_WT + idx] = 1.0f / fmaxf(r, 1e-10f);
}

// -------- pass B+C (MFMA): V_k = (A diag(g_k)) A^T via 16x16x32 bf16, ISS fused --------
// A = [Xr;Xi] (12 rows x 2048), staged per 256-t chunk into 7 bf16 LDS planes
// (k=0..5 scaled by g_k, plane 6 unscaled). Wave k runs the MFMA chain for k.
// Layout-agnostic: A-frag and B-frag read identical per-lane K-patterns from the
// same t-data, so any bijective HW k-map yields sum_t g*A[i,t]*A[j,t].
__global__ __launch_bounds__(384) void passBC(const float2* __restrict__ Xt,
                                              float* __restrict__ ws,
                                              const float* __restrict__ pin,
                                              float* __restrict__ pout) {
    // plane stride: 16 rows x 528 B (512 data + 16 pad -> 2-way bank conflicts max)
    __shared__ __align__(16) char AB[7 * 8448];
    __shared__ float sc[12];
    const int bid = blockIdx.x, tid = threadIdx.x;
    const int wv = tid >> 6, lane = tid & 63;

    // convergence check
    {
        float d2 = 0.f, o2 = 0.f;
        for (int i = tid; i < F_DIM; i += 384) { d2 += pin[2 * i]; o2 += pin[2 * i + 1]; }
#pragma unroll
        for (int d = 1; d < 64; d <<= 1) { d2 += __shfl_xor(d2, d); o2 += __shfl_xor(o2, d); }
        if (lane == 0) { sc[wv * 2] = d2; sc[wv * 2 + 1] = o2; }
        __syncthreads();
        d2 = 0.f; o2 = 0.f;
#pragma unroll
        for (int w = 0; w < 6; ++w) { d2 += sc[w * 2]; o2 += sc[w * 2 + 1]; }
        float rel = sqrtf(d2) / fmaxf(sqrtf(o2), 1.1920929e-07f);
        __syncthreads();
        if (rel < 1e-5f) {
            if (tid == 0) { pout[2 * bid] = 0.0f; pout[2 * bid + 1] = 1.0f; }
            return;
        }
    }

    // zero all planes once (rows 12..15 stay zero through all chunks)
    for (int i = tid; i < 7 * 8448 / 4; i += 384) ((unsigned*)AB)[i] = 0;
    __syncthreads();

    const int f = bid;
    const float2* xb = Xt + (size_t)f * 6 * T_DIM;
    const float* wt = ws + OFF_WT;

    f32x4 acc0 = {0.f, 0.f, 0.f, 0.f};
    f32x4 acc1 = {0.f, 0.f, 0.f, 0.f};
    const int rc = lane & 15;          // A-row / B-col index for this lane
    const int G  = lane >> 4;
    const int rdbase = rc * 528 + G * 16;

    for (int c = 0; c < 8; ++c) {
        const int t0 = c * 256;
        // ---- stage chunk: 768 items = (m 0..5) x (tp 0..127), 2 t's per item ----
        for (int it = tid; it < 768; it += 384) {
            const int m = it >> 7, tp = it & 127;
            const int t = 2 * tp;
            float4 xv = *(const float4*)(xb + (size_t)m * T_DIM + t0 + t); // (re0,im0,re1,im1)
            char* rowR = AB + m * 528 + 4 * tp;
            char* rowI = AB + (6 + m) * 528 + 4 * tp;
            *(unsigned*)(rowR + 6 * 8448) = pack2bf(xv.x, xv.z);
            *(unsigned*)(rowI + 6 * 8448) = pack2bf(xv.y, xv.w);
#pragma unroll
            for (int k = 0; k < 6; ++k) {
                float2 g = *(const float2*)(wt + k * T_DIM + t0 + t);
                *(unsigned*)(rowR + k * 8448) = pack2bf(g.x * xv.x, g.y * xv.z);
                *(unsigned*)(rowI + k * 8448) = pack2bf(g.x * xv.y, g.y * xv.w);
            }
        }
        __syncthreads();
        // ---- MFMA: wave wv accumulates S_wv over this chunk (K = 256 = 8 steps) ----
        {
            const char* pk = AB + wv * 8448 + rdbase;
            const char* pu = AB + 6 * 8448 + rdbase;
#pragma unroll
            for (int s = 0; s < 8; s += 2) {
                bf16x8 a0 = *(const bf16x8*)(pk + s * 64);
                bf16x8 b0 = *(const bf16x8*)(pu + s * 64);
                acc0 = __builtin_amdgcn_mfma_f32_16x16x32_bf16(a0, b0, acc0, 0, 0, 0);
                bf16x8 a1 = *(const bf16x8*)(pk + s * 64 + 64);
                bf16x8 b1 = *(const bf16x8*)(pu + s * 64 + 64);
                acc1 = __builtin_amdgcn_mfma_f32_16x16x32_bf16(a1, b1, acc1, 0, 0, 0);
            }
        }
        __syncthreads();
    }

    // ---- dump S_k (16x16 f32) into LDS (reuse AB region) ----
    float* S  = (float*)AB;            // 6*256 f32 = 6144 B
    float* VL = (float*)(AB + 6144);   // 432 f32
    {
        float* Sk = S + wv * 256;
#pragma unroll
        for (int r = 0; r < 4; ++r)
            Sk[(4 * G + r) * 16 + rc] = acc0[r] + acc1[r];  // D: row=4G+r, col=lane&15
    }
    __syncthreads();

    // ---- assemble V: V_re = S[a][b]+S[6+a][6+b], V_im = S[6+a][b]-S[a][6+b] ----
    if (tid < 216) {
        const int kk = tid / 36, e = tid % 36;
        const float* Sk = S + kk * 256;
        const float inv_t = 1.0f / (float)T_DIM;
        if (e < 6) {
            float re = (Sk[e * 16 + e] + Sk[(6 + e) * 16 + (6 + e)]) * inv_t;
            VL[((kk * 6 + e) * 6 + e) * 2]     = re + 1e-6f;
            VL[((kk * 6 + e) * 6 + e) * 2 + 1] = 0.f;
        } else if (e < 21) {
            int p = e - 6;
            int a = (p < 1) ? 1 : (p < 3) ? 2 : (p < 6) ? 3 : (p < 10) ? 4 : 5;
            int b = p - a * (a - 1) / 2;
            float re = (Sk[a * 16 + b] + Sk[(6 + a) * 16 + (6 + b)]) * inv_t;
            VL[((kk * 6 + a) * 6 + b) * 2] = re;
            VL[((kk * 6 + b) * 6 + a) * 2] = re;
        } else {
            int p = e - 21;
            int a = (p < 1) ? 1 : (p < 3) ? 2 : (p < 6) ? 3 : (p < 10) ? 4 : 5;
            int b = p - a * (a - 1) / 2;
            float im = (Sk[(6 + a) * 16 + b] - Sk[a * 16 + (6 + b)]) * inv_t;
            VL[((kk * 6 + a) * 6 + b) * 2 + 1] =  im;
            VL[((kk * 6 + b) * 6 + a) * 2 + 1] = -im;
        }
    }
    __syncthreads();

    // ---- ISS update: wave 0 only, wave-synchronous ----
    if (wv == 0) {
        const int m = lane;
        const bool act = (m < 6);
        float w6[6][2], wold[6][2];
#pragma unroll
        for (int a = 0; a < 6; ++a) {
            w6[a][0] = 0.f; w6[a][1] = 0.f; wold[a][0] = 0.f; wold[a][1] = 0.f;
        }
        float* Wp = ws + OFF_W + ((size_t)f * 36 + (act ? m : 0) * 6) * 2;
        if (act) {
#pragma unroll
            for (int a = 0; a < 6; ++a) {
                w6[a][0] = Wp[2 * a]; w6[a][1] = Wp[2 * a + 1];
                wold[a][0] = w6[a][0]; wold[a][1] = w6[a][1];
            }
        }
        const float2* VL2 = (const float2*)VL;
        for (int kk = 0; kk < 6; ++kk) {
            float wk[6][2];
#pragma unroll
            for (int a = 0; a < 6; ++a) {
                wk[a][0] = __shfl(w6[a][0], kk);
                wk[a][1] = __shfl(w6[a][1], kk);
            }
            if (act) {
                float t6[6][2];
#pragma unroll
                for (int a = 0; a < 6; ++a) {
                    float tr = 0.f, ti = 0.f;
#pragma unroll
                    for (int b = 0; b < 6; ++b) {
                        float2 vv = VL2[m * 36 + a * 6 + b];
                        tr += vv.x * wk[b][0] + vv.y * wk[b][1];
                        ti += vv.y * wk[b][0] - vv.x * wk[b][1];
                    }
                    t6[a][0] = tr; t6[a][1] = ti;
                }
                float quad = 0.f, nr = 0.f, ni = 0.f;
#pragma unroll
                for (int a = 0; a < 6; ++a) {
                    quad += wk[a][0] * t6[a][0] - wk[a][1] * t6[a][1];
                    nr   += w6[a][0] * t6[a][0] - w6[a][1] * t6[a][1];
                    ni   += w6[a][0] * t6[a][1] + w6[a][1] * t6[a][0];
                }
                float denom = fmaxf(quad, 1e-10f);
                float vkr, vki;
                if (m == kk) { vkr = 1.0f - 1.0f / sqrtf(denom); vki = 0.0f; }
                else { float inv = 1.0f / denom; vkr = nr * inv; vki = ni * inv; }
#pragma unroll
                for (int a = 0; a < 6; ++a) {
                    w6[a][0] -= vkr * wk[a][0] - vki * wk[a][1];
                    w6[a][1] -= vkr * wk[a][1] + vki * wk[a][0];
                }
            }
        }
        float d2 = 0.f, o2 = 0.f;
        if (act) {
#pragma unroll
            for (int a = 0; a < 6; ++a) {
                Wp[2 * a] = w6[a][0]; Wp[2 * a + 1] = w6[a][1];
                float dr = w6[a][0] - wold[a][0], di = w6[a][1] - wold[a][1];
                d2 += dr * dr + di * di;
                o2 += wold[a][0] * wold[a][0] + wold[a][1] * wold[a][1];
            }
        }
#pragma unroll
        for (int d = 1; d < 8; d <<= 1) {
            d2 += __shfl_xor(d2, d);
            o2 += __shfl_xor(o2, d);
        }
        if (lane == 0) {
            pout[2 * bid]     = d2;
            pout[2 * bid + 1] = o2;
        }
    }
}

// -------- final: out[k,t,f] = sum_m W[f,k,m] X[m,t,f], W cached in registers --------
__global__ __launch_bounds__(256) void finalY(const float2* __restrict__ X,
                                              const float* __restrict__ ws,
                                              float2* __restrict__ out) {
    const int f  = blockIdx.y * 256 + threadIdx.x;
    const int t0 = blockIdx.x * 4;
    if (f >= F_DIM) return;
    const float2* Wf = (const float2*)(ws + OFF_W) + (size_t)f * 36;
    float2 w[36];
#pragma unroll
    for (int i = 0; i < 36; ++i) w[i] = Wf[i];
#pragma unroll
    for (int tl = 0; tl < 4; ++tl) {
        int t = t0 + tl;
        float2 x[6];
#pragma unroll
        for (int m = 0; m < 6; ++m) x[m] = X[((size_t)m * T_DIM + t) * F_DIM + f];
#pragma unroll
        for (int k = 0; k < 6; ++k) {
            float yr = 0.f, yi = 0.f;
#pragma unroll
            for (int m = 0; m < 6; ++m) {
                float2 wk = w[k * 6 + m];
                yr += wk.x * x[m].x - wk.y * x[m].y;
                yi += wk.x * x[m].y + wk.y * x[m].x;
            }
            out[((size_t)k * T_DIM + t) * F_DIM + f] = make_float2(yr, yi);
        }
    }
}

extern "C" void kernel_launch(void* const* d_in, const int* in_sizes, int n_in,
                              void* d_out, int out_size, void* d_ws, size_t ws_size,
                              hipStream_t stream) {
    (void)in_sizes; (void)n_in; (void)out_size; (void)ws_size;
    const float2* X = (const float2*)d_in[0];
    float* ws = (float*)d_ws;
    float2* out = (float2*)d_out;
    float2* Xt = out;  // transposed X lives in d_out until finalY overwrites it

    transp<<<dim3(64, 17, 6), 256, 0, stream>>>(X, Xt, ws);
    for (int it = 0; it < N_ITER; ++it) {
        const float* pin = ws + (((it + 1) & 1) ? OFF_P1 : OFF_P0);
        float* pout      = ws + (((it    ) & 1) ? OFF_P1 : OFF_P0);
        passA1<<<dim3(32, 17), 256, 0, stream>>>(Xt, ws, pin);
        passA2<<<48, 256, 0, stream>>>(ws, pin);
        passBC<<<F_DIM, 384, 0, stream>>>(Xt, ws, pin, pout);
    }
    finalY<<<dim3(T_DIM / 4, 3), 256, 0, stream>>>(X, ws, out);
}

// Round 8
// 620.095 us; speedup vs baseline: 3.1951x; 1.2962x over previous
//
#include <hip/hip_runtime.h>
#include <hip/hip_bf16.h>
#include <math.h>

#define T_DIM 2048
#define F_DIM 513
#define N_ITER 10

// ws float offsets
#define OFF_W    0        // 513*36*2 = 36936 floats (complex W[f][k][m])
#define OFF_WT   36936    // 6*2048   = 12288 floats
#define OFF_P0   49224    // 513*2 partial pairs (parity 0)
#define OFF_P1   50250    // 513*2 partial pairs (parity 1)
#define OFF_R2   51276    // 33*6*2048 = 405504 floats (r2 partials per 16-f chunk)
#define OFF_VP   51276    // 513*4*216 = 443232 floats (V partials) -- time-shared with R2

typedef __attribute__((ext_vector_type(8))) short bf16x8;
typedef __attribute__((ext_vector_type(4))) float f32x4;

static __device__ inline unsigned pack2bf(float a, float b) {
    union { __hip_bfloat16 h; unsigned short u; } ca, cb;
    ca.h = __float2bfloat16(a);
    cb.h = __float2bfloat16(b);
    return (unsigned)ca.u | ((unsigned)cb.u << 16);
}

// -------- transpose X (K,T,F) -> Xt (F,K,T), + init W=I and partial buffers --------
__global__ __launch_bounds__(256) void transp(const float2* __restrict__ X,
                                              float2* __restrict__ Xt,
                                              float* __restrict__ ws) {
    const int fb  = blockIdx.x + 64 * (blockIdx.y + 17 * blockIdx.z);
    const int tid = threadIdx.x;
    if (fb < 73) {
        int idx = fb * 256 + tid;
        if (idx < F_DIM * 36) {
            int e = idx % 36;
            ws[OFF_W + 2 * idx]     = ((e / 6) == (e % 6)) ? 1.0f : 0.0f;
            ws[OFF_W + 2 * idx + 1] = 0.0f;
        }
    } else if (fb < 78) {
        int idx = (fb - 73) * 256 + tid;
        if (idx < 2 * F_DIM) { ws[OFF_P0 + idx] = 1.0f; ws[OFF_P1 + idx] = 1.0f; }
    }

    __shared__ float2 tile[32][33];
    const int k  = blockIdx.z;
    const int t0 = blockIdx.x * 32;
    const int f0 = blockIdx.y * 32;
    const int tx = tid & 31, ty = tid >> 5;
#pragma unroll
    for (int j = 0; j < 4; ++j) {
        int t = t0 + ty + j * 8;
        int f = f0 + tx;
        if (f < F_DIM) tile[ty + j * 8][tx] = X[((size_t)k * T_DIM + t) * F_DIM + f];
    }
    __syncthreads();
#pragma unroll
    for (int j = 0; j < 4; ++j) {
        int f = f0 + ty + j * 8;
        int t = t0 + tx;
        if (f < F_DIM) Xt[((size_t)f * 6 + k) * T_DIM + t] = tile[tx][ty + j * 8];
    }
}

// -------- pass A1: r2 partials. block=(t-chunk of 64, f-chunk of 16), lanes over t --------
__global__ __launch_bounds__(256) void passA1(const float2* __restrict__ Xt,
                                              float* __restrict__ ws,
                                              const float* __restrict__ pin) {
    __shared__ float r2s[4][6][65];
    __shared__ float sc[8];
    const int tid = threadIdx.x, wv = tid >> 6, lane = tid & 63;
    {
        float d2 = 0.f, o2 = 0.f;
        for (int i = tid; i < F_DIM; i += 256) { d2 += pin[2 * i]; o2 += pin[2 * i + 1]; }
#pragma unroll
        for (int d = 1; d < 64; d <<= 1) { d2 += __shfl_xor(d2, d); o2 += __shfl_xor(o2, d); }
        if (lane == 0) { sc[wv * 2] = d2; sc[wv * 2 + 1] = o2; }
        __syncthreads();
        d2 = sc[0] + sc[2] + sc[4] + sc[6];
        o2 = sc[1] + sc[3] + sc[5] + sc[7];
        float rel = sqrtf(d2) / fmaxf(sqrtf(o2), 1.1920929e-07f);
        if (rel < 1e-5f) return;
    }
    const int t  = blockIdx.x * 64 + lane;
    const int fc = blockIdx.y;
    const float2* Wc = (const float2*)(ws + OFF_W);
    float acc[6] = {0.f, 0.f, 0.f, 0.f, 0.f, 0.f};
#pragma unroll
    for (int i = 0; i < 4; ++i) {
        const int f = fc * 16 + wv * 4 + i;
        if (f < F_DIM) {
            const float2* xf = Xt + (size_t)f * 6 * T_DIM + t;
            float2 x[6];
#pragma unroll
            for (int m = 0; m < 6; ++m) x[m] = xf[(size_t)m * T_DIM];
            const float2* wf = Wc + f * 36;
#pragma unroll
            for (int k = 0; k < 6; ++k) {
                float yr = 0.f, yi = 0.f;
#pragma unroll
                for (int m = 0; m < 6; ++m) {
                    float2 wk = wf[k * 6 + m];
                    yr += wk.x * x[m].x - wk.y * x[m].y;
                    yi += wk.x * x[m].y + wk.y * x[m].x;
                }
                acc[k] += yr * yr + yi * yi;
            }
        }
    }
#pragma unroll
    for (int k = 0; k < 6; ++k) r2s[wv][k][lane] = acc[k];
    __syncthreads();
    for (int v = tid; v < 384; v += 256) {
        int k = v >> 6, l = v & 63;
        float s = r2s[0][k][l] + r2s[1][k][l] + r2s[2][k][l] + r2s[3][k][l];
        ws[OFF_R2 + ((size_t)fc * 6 + k) * T_DIM + blockIdx.x * 64 + l] = s;
    }
}

// -------- pass A2: wt[k,t] = 1/clip(sqrt(clip(sum_fc r2part))) --------
__global__ __launch_bounds__(256) void passA2(float* __restrict__ ws,
                                              const float* __restrict__ pin) {
    __shared__ float sc[8];
    const int tid = threadIdx.x, wv = tid >> 6, lane = tid & 63;
    {
        float d2 = 0.f, o2 = 0.f;
        for (int i = tid; i < F_DIM; i += 256) { d2 += pin[2 * i]; o2 += pin[2 * i + 1]; }
#pragma unroll
        for (int d = 1; d < 64; d <<= 1) { d2 += __shfl_xor(d2, d); o2 += __shfl_xor(o2, d); }
        if (lane == 0) { sc[wv * 2] = d2; sc[wv * 2 + 1] = o2; }
        __syncthreads();
        d2 = sc[0] + sc[2] + sc[4] + sc[6];
        o2 = sc[1] + sc[3] + sc[5] + sc[7];
        float rel = sqrtf(d2) / fmaxf(sqrtf(o2), 1.1920929e-07f);
        if (rel < 1e-5f) return;
    }
    const int idx = blockIdx.x * 256 + tid;    // = k*T_DIM + t
    float s = 0.f;
#pragma unroll
    for (int fc = 0; fc < 33; ++fc) s += ws[OFF_R2 + (size_t)fc * 6 * T_DIM + idx];
    float r = sqrtf(fmaxf(s, 1e-10f));
    ws[OFF_WT + idx] = 1.0f / fmaxf(r, 1e-10f);
}

// -------- pass B (MFMA): S_k partials over a 512-t quarter; scaled operand built
// in registers from the unscaled fragment (one LDS plane + g-table only).
// Layout-agnostic Gram: A-frag and B-frag use identical (lane,elem)->t maps. --------
__global__ __launch_bounds__(384) void passB(const float2* __restrict__ Xt,
                                             float* __restrict__ ws,
                                             const float* __restrict__ pin) {
    __shared__ __align__(16) char plane[16 * 528];   // 16 rows x 528B bf16 (512 data + 16 pad)
    __shared__ __align__(16) float gbuf[6][256];
    __shared__ float sc[12];
    const int tid = threadIdx.x, wv = tid >> 6, lane = tid & 63;

    {
        float d2 = 0.f, o2 = 0.f;
        for (int i = tid; i < F_DIM; i += 384) { d2 += pin[2 * i]; o2 += pin[2 * i + 1]; }
#pragma unroll
        for (int d = 1; d < 64; d <<= 1) { d2 += __shfl_xor(d2, d); o2 += __shfl_xor(o2, d); }
        if (lane == 0) { sc[wv * 2] = d2; sc[wv * 2 + 1] = o2; }
        __syncthreads();
        d2 = 0.f; o2 = 0.f;
#pragma unroll
        for (int w = 0; w < 6; ++w) { d2 += sc[w * 2]; o2 += sc[w * 2 + 1]; }
        float rel = sqrtf(d2) / fmaxf(sqrtf(o2), 1.1920929e-07f);
        __syncthreads();
        if (rel < 1e-5f) return;
    }

    const int f = blockIdx.x, tq = blockIdx.y;
    const float2* xb = Xt + (size_t)f * 6 * T_DIM;

    // zero rows 12..15 once (528 dwords)
    for (int i = tid; i < 528; i += 384) ((unsigned*)(plane + 12 * 528))[i] = 0;

    f32x4 acc0 = {0.f, 0.f, 0.f, 0.f};
    f32x4 acc1 = {0.f, 0.f, 0.f, 0.f};
    const int rc = lane & 15;
    const int G  = lane >> 4;
    const char* pu = plane + rc * 528 + G * 16;
    const float* gk = &gbuf[wv][0] + G * 8;

    for (int c = 0; c < 2; ++c) {
        const int t0 = tq * 512 + c * 256;
        __syncthreads();   // prior MFMA reads done before rewrite
        // stage g-table: 6k x 256t, coalesced
        for (int i = tid; i < 1536; i += 384) {
            int kk = i >> 8, toff = i & 255;
            gbuf[kk][toff] = ws[OFF_WT + kk * T_DIM + t0 + toff];
        }
        // stage unscaled bf16 plane: 6 m x 128 float4 (2 complex t's each)
        for (int it = tid; it < 768; it += 384) {
            int m = it >> 7, q = it & 127;
            float4 xv = *(const float4*)(xb + (size_t)m * T_DIM + t0 + 2 * q);
            *(unsigned*)(plane + m * 528 + 4 * q)       = pack2bf(xv.x, xv.z);
            *(unsigned*)(plane + (6 + m) * 528 + 4 * q) = pack2bf(xv.y, xv.w);
        }
        __syncthreads();
        // MFMA: 8 K-steps of 32; scale a-frag in registers
#pragma unroll
        for (int s = 0; s < 8; ++s) {
            bf16x8 b = *(const bf16x8*)(pu + s * 64);
            f32x4 gA = *(const f32x4*)(gk + s * 32);
            f32x4 gB = *(const f32x4*)(gk + s * 32 + 4);
            const unsigned* bu = (const unsigned*)&b;
            bf16x8 a;
            unsigned* au = (unsigned*)&a;
            au[0] = pack2bf(__uint_as_float(bu[0] << 16) * gA[0],
                            __uint_as_float(bu[0] & 0xffff0000u) * gA[1]);
            au[1] = pack2bf(__uint_as_float(bu[1] << 16) * gA[2],
                            __uint_as_float(bu[1] & 0xffff0000u) * gA[3]);
            au[2] = pack2bf(__uint_as_float(bu[2] << 16) * gB[0],
                            __uint_as_float(bu[2] & 0xffff0000u) * gB[1]);
            au[3] = pack2bf(__uint_as_float(bu[3] << 16) * gB[2],
                            __uint_as_float(bu[3] & 0xffff0000u) * gB[3]);
            if (s & 1) acc1 = __builtin_amdgcn_mfma_f32_16x16x32_bf16(a, b, acc1, 0, 0, 0);
            else       acc0 = __builtin_amdgcn_mfma_f32_16x16x32_bf16(a, b, acc0, 0, 0, 0);
        }
    }
    __syncthreads();

    // dump S_k (16x16 f32) into LDS (reuse plane region, 6144B)
    float* S = (float*)plane;
    {
        float* Sk = S + wv * 256;
#pragma unroll
        for (int r = 0; r < 4; ++r)
            Sk[(4 * G + r) * 16 + rc] = acc0[r] + acc1[r];   // D: row=4G+r, col=lane&15
    }
    __syncthreads();

    // assemble V partials (no 1/T, no REG yet) -> global
    if (tid < 216) {
        const int kk = tid / 36, e = tid % 36;
        const float* Sk = S + kk * 256;
        float val;
        if (e < 6) {
            val = Sk[e * 16 + e] + Sk[(6 + e) * 16 + (6 + e)];
        } else if (e < 21) {
            int p = e - 6;
            int a = (p < 1) ? 1 : (p < 3) ? 2 : (p < 6) ? 3 : (p < 10) ? 4 : 5;
            int b = p - a * (a - 1) / 2;
            val = Sk[a * 16 + b] + Sk[(6 + a) * 16 + (6 + b)];
        } else {
            int p = e - 21;
            int a = (p < 1) ? 1 : (p < 3) ? 2 : (p < 6) ? 3 : (p < 10) ? 4 : 5;
            int b = p - a * (a - 1) / 2;
            val = Sk[(6 + a) * 16 + b] - Sk[a * 16 + (6 + b)];
        }
        ws[OFF_VP + ((size_t)f * 4 + tq) * 216 + tid] = val;
    }
}

// -------- pass C: sum V partials, build V in LDS, wave-synchronous ISS update --------
__global__ __launch_bounds__(64) void passC(float* __restrict__ ws,
                                            const float* __restrict__ pin,
                                            float* __restrict__ pout) {
    __shared__ float VL[432];
    const int f = blockIdx.x;
    const int lane = threadIdx.x;
    {
        float d2 = 0.f, o2 = 0.f;
        for (int i = lane; i < F_DIM; i += 64) { d2 += pin[2 * i]; o2 += pin[2 * i + 1]; }
#pragma unroll
        for (int d = 1; d < 64; d <<= 1) { d2 += __shfl_xor(d2, d); o2 += __shfl_xor(o2, d); }
        float rel = sqrtf(d2) / fmaxf(sqrtf(o2), 1.1920929e-07f);
        if (rel < 1e-5f) {
            if (lane == 0) { pout[2 * f] = 0.0f; pout[2 * f + 1] = 1.0f; }
            return;
        }
    }
    for (int v = lane; v < 216; v += 64) {
        float sum = 0.f;
#pragma unroll
        for (int tq = 0; tq < 4; ++tq)
            sum += ws[OFF_VP + ((size_t)f * 4 + tq) * 216 + v];
        sum *= (1.0f / (float)T_DIM);
        int kk = v / 36, e = v % 36;
        if (e < 6) {
            VL[((kk * 6 + e) * 6 + e) * 2]     = sum + 1e-6f;
            VL[((kk * 6 + e) * 6 + e) * 2 + 1] = 0.f;
        } else if (e < 21) {
            int p = e - 6;
            int a = (p < 1) ? 1 : (p < 3) ? 2 : (p < 6) ? 3 : (p < 10) ? 4 : 5;
            int b = p - a * (a - 1) / 2;
            VL[((kk * 6 + a) * 6 + b) * 2] = sum;
            VL[((kk * 6 + b) * 6 + a) * 2] = sum;
        } else {
            int p = e - 21;
            int a = (p < 1) ? 1 : (p < 3) ? 2 : (p < 6) ? 3 : (p < 10) ? 4 : 5;
            int b = p - a * (a - 1) / 2;
            VL[((kk * 6 + a) * 6 + b) * 2 + 1] =  sum;
            VL[((kk * 6 + b) * 6 + a) * 2 + 1] = -sum;
        }
    }
    __syncthreads();

    const int m = lane;
    const bool act = (m < 6);
    float w6[6][2], wold[6][2];
#pragma unroll
    for (int a = 0; a < 6; ++a) {
        w6[a][0] = 0.f; w6[a][1] = 0.f; wold[a][0] = 0.f; wold[a][1] = 0.f;
    }
    float* Wp = ws + OFF_W + ((size_t)f * 36 + (act ? m : 0) * 6) * 2;
    if (act) {
#pragma unroll
        for (int a = 0; a < 6; ++a) {
            w6[a][0] = Wp[2 * a]; w6[a][1] = Wp[2 * a + 1];
            wold[a][0] = w6[a][0]; wold[a][1] = w6[a][1];
        }
    }
    const float2* VL2 = (const float2*)VL;
    for (int kk = 0; kk < 6; ++kk) {
        float wk[6][2];
#pragma unroll
        for (int a = 0; a < 6; ++a) {
            wk[a][0] = __shfl(w6[a][0], kk);
            wk[a][1] = __shfl(w6[a][1], kk);
        }
        if (act) {
            float t6[6][2];
#pragma unroll
            for (int a = 0; a < 6; ++a) {
                float tr = 0.f, ti = 0.f;
#pragma unroll
                for (int b = 0; b < 6; ++b) {
                    float2 vv = VL2[m * 36 + a * 6 + b];
                    tr += vv.x * wk[b][0] + vv.y * wk[b][1];
                    ti += vv.y * wk[b][0] - vv.x * wk[b][1];
                }
                t6[a][0] = tr; t6[a][1] = ti;
            }
            float quad = 0.f, nr = 0.f, ni = 0.f;
#pragma unroll
            for (int a = 0; a < 6; ++a) {
                quad += wk[a][0] * t6[a][0] - wk[a][1] * t6[a][1];
                nr   += w6[a][0] * t6[a][0] - w6[a][1] * t6[a][1];
                ni   += w6[a][0] * t6[a][1] + w6[a][1] * t6[a][0];
            }
            float denom = fmaxf(quad, 1e-10f);
            float vkr, vki;
            if (m == kk) { vkr = 1.0f - 1.0f / sqrtf(denom); vki = 0.0f; }
            else { float inv = 1.0f / denom; vkr = nr * inv; vki = ni * inv; }
#pragma unroll
            for (int a = 0; a < 6; ++a) {
                w6[a][0] -= vkr * wk[a][0] - vki * wk[a][1];
                w6[a][1] -= vkr * wk[a][1] + vki * wk[a][0];
            }
        }
    }
    float d2 = 0.f, o2 = 0.f;
    if (act) {
#pragma unroll
        for (int a = 0; a < 6; ++a) {
            Wp[2 * a] = w6[a][0]; Wp[2 * a + 1] = w6[a][1];
            float dr = w6[a][0] - wold[a][0], di = w6[a][1] - wold[a][1];
            d2 += dr * dr + di * di;
            o2 += wold[a][0] * wold[a][0] + wold[a][1] * wold[a][1];
        }
    }
#pragma unroll
    for (int d = 1; d < 8; d <<= 1) {
        d2 += __shfl_xor(d2, d);
        o2 += __shfl_xor(o2, d);
    }
    if (lane == 0) {
        pout[2 * f]     = d2;
        pout[2 * f + 1] = o2;
    }
}

// -------- final: out[k,t,f] = sum_m W[f,k,m] X[m,t,f], W cached in registers --------
__global__ __launch_bounds__(256) void finalY(const float2* __restrict__ X,
                                              const float* __restrict__ ws,
                                              float2* __restrict__ out) {
    const int f  = blockIdx.y * 256 + threadIdx.x;
    const int t0 = blockIdx.x * 4;
    if (f >= F_DIM) return;
    const float2* Wf = (const float2*)(ws + OFF_W) + (size_t)f * 36;
    float2 w[36];
#pragma unroll
    for (int i = 0; i < 36; ++i) w[i] = Wf[i];
#pragma unroll
    for (int tl = 0; tl < 4; ++tl) {
        int t = t0 + tl;
        float2 x[6];
#pragma unroll
        for (int m = 0; m < 6; ++m) x[m] = X[((size_t)m * T_DIM + t) * F_DIM + f];
#pragma unroll
        for (int k = 0; k < 6; ++k) {
            float yr = 0.f, yi = 0.f;
#pragma unroll
            for (int m = 0; m < 6; ++m) {
                float2 wk = w[k * 6 + m];
                yr += wk.x * x[m].x - wk.y * x[m].y;
                yi += wk.x * x[m].y + wk.y * x[m].x;
            }
            out[((size_t)k * T_DIM + t) * F_DIM + f] = make_float2(yr, yi);
        }
    }
}

extern "C" void kernel_launch(void* const* d_in, const int* in_sizes, int n_in,
                              void* d_out, int out_size, void* d_ws, size_t ws_size,
                              hipStream_t stream) {
    (void)in_sizes; (void)n_in; (void)out_size; (void)ws_size;
    const float2* X = (const float2*)d_in[0];
    float* ws = (float*)d_ws;
    float2* out = (float2*)d_out;
    float2* Xt = out;  // transposed X lives in d_out until finalY overwrites it

    transp<<<dim3(64, 17, 6), 256, 0, stream>>>(X, Xt, ws);
    for (int it = 0; it < N_ITER; ++it) {
        const float* pin = ws + (((it + 1) & 1) ? OFF_P1 : OFF_P0);
        float* pout      = ws + (((it    ) & 1) ? OFF_P1 : OFF_P0);
        passA1<<<dim3(32, 33), 256, 0, stream>>>(Xt, ws, pin);
        passA2<<<48, 256, 0, stream>>>(ws, pin);
        passB<<<dim3(F_DIM, 4), 384, 0, stream>>>(Xt, ws, pin);
        passC<<<F_DIM, 64, 0, stream>>>(ws, pin, pout);
    }
    finalY<<<dim3(T_DIM / 4, 3), 256, 0, stream>>>(X, ws, out);
}